// Round 4
// baseline (2301.886 us; speedup 1.0000x reference)
//
#include <hip/hip_runtime.h>

typedef _Float16 f16;
typedef _Float16 f16x4 __attribute__((ext_vector_type(4)));
typedef _Float16 f16x8 __attribute__((ext_vector_type(8)));
typedef float f32x4 __attribute__((ext_vector_type(4)));

#define N_ 256
#define T_ 64
#define D_ 1024
#define H_ 1024
#define K3 3072
#define G4 4096

// ---- transpose+pack Wx/Wh/Wattn (fp32 [k][j]) -> W3P fragment-major f16 --------
// W3P[((ht*4+g)*96 + s)*512 + m16*32 + quad*8 + e]; row j = g*1024+ht*16+m16,
// col k = s*32 + quad*8 + e. Each wave B-fragment load = contiguous 1 KB.
__global__ void k_transpose(const float* __restrict__ Wx, const float* __restrict__ Wh,
                            const float* __restrict__ Wattn, f16* __restrict__ W3P) {
    __shared__ float tile[32][33];
    int j0 = blockIdx.x * 32;   // 128 blocks over j (4096)
    int k0 = blockIdx.y * 32;   // 96 blocks over k (3072); s = blockIdx.y
    int tx = threadIdx.x;       // 32
    int ty = threadIdx.y;       // 8
    for (int i = 0; i < 4; i++) {
        int k = k0 + ty + i * 8;
        const float* W = (k < 1024) ? Wx : ((k < 2048) ? Wh : Wattn);
        int kr = k & 1023;
        tile[ty + i * 8][tx] = W[(size_t)kr * 4096 + j0 + tx];
    }
    __syncthreads();
    for (int i = 0; i < 4; i++) {
        int j = j0 + ty + i * 8;
        int ht = (j & 1023) >> 4;
        int g = j >> 10;
        int m16 = j & 15;
        W3P[(size_t)((ht * 4 + g) * 96 + blockIdx.y) * 512 + m16 * 32 + tx] =
            (f16)tile[tx][ty + i * 8];
    }
}

// ---- pack x (fp32 [n][t][k]) -> xp (f16 [t][s][n][32]) --------------------------
__global__ void k_packX(const float* __restrict__ x, f16* __restrict__ xp) {
    int bid = blockIdx.x;          // n*64 + t
    int n = bid >> 6;
    int t = bid & 63;
    int k = threadIdx.x * 8;       // 128 threads
    const float* src = x + ((size_t)(n * 64 + t)) * 1024 + k;
    float4 v0 = *(const float4*)src;
    float4 v1 = *(const float4*)(src + 4);
    f16x8 h;
    h[0] = (f16)v0.x; h[1] = (f16)v0.y; h[2] = (f16)v0.z; h[3] = (f16)v0.w;
    h[4] = (f16)v1.x; h[5] = (f16)v1.y; h[6] = (f16)v1.z; h[7] = (f16)v1.w;
    int s = k >> 5, o = k & 31;
    *(f16x8*)(xp + ((size_t)(t * 32 + s) * 256 + n) * 32 + o) = h;
}

// ---- pack A (fp32 [n][h][l]) -> A16T (f16 [n][l][h]) ----------------------------
__global__ void k_packA(const float* __restrict__ A, f16* __restrict__ A16T) {
    __shared__ f16 tile[256][17];
    int n = blockIdx.x;
    int tid = threadIdx.x;
    for (int c4 = 0; c4 < 4; c4++) {
        int h = c4 * 256 + tid;
        const float* Ap = A + (size_t)n * 16384 + h * 16;
#pragma unroll
        for (int l = 0; l < 16; l++) tile[tid][l] = (f16)Ap[l];
        __syncthreads();
        int l = tid >> 4;
        int hs = (tid & 15) * 16;
        f16 v[16];
#pragma unroll
        for (int j = 0; j < 16; j++) v[j] = tile[hs + j][l];
        f16* dst = A16T + (size_t)n * 16384 + l * 1024 + c4 * 256 + hs;
        *(f16x8*)dst = *(f16x8*)v;
        *(f16x8*)(dst + 8) = *(f16x8*)(v + 8);
        __syncthreads();
    }
}

// ---- init: h0 = c0 = mean(A); zp0 packed; spart slab0 = h0.A; zero other slabs --
__global__ void k_init(const float* __restrict__ A, f16* __restrict__ zp0,
                       float* __restrict__ c, float* __restrict__ spart) {
    int n = blockIdx.x;
    int tid = threadIdx.x;
    __shared__ float sred[256][16];
    float s[16];
#pragma unroll
    for (int l = 0; l < 16; l++) s[l] = 0.f;
    for (int i = 0; i < 4; i++) {
        int h = tid + i * 256;
        const float* Ap = A + (size_t)n * 16384 + h * 16;
        float a[16];
        float sum = 0.f;
#pragma unroll
        for (int l = 0; l < 16; l++) { a[l] = Ap[l]; sum += a[l]; }
        float h0 = sum * (1.f / 16.f);
        c[n * 1024 + h] = h0;
        zp0[((size_t)(h >> 5) * 256 + n) * 32 + (h & 31)] = (f16)h0;
#pragma unroll
        for (int l = 0; l < 16; l++) s[l] += h0 * a[l];
    }
#pragma unroll
    for (int l = 0; l < 16; l++) sred[tid][l] = s[l];
    __syncthreads();
    for (int st = 128; st > 0; st >>= 1) {
        if (tid < st) {
#pragma unroll
            for (int l = 0; l < 16; l++) sred[tid][l] += sred[tid + st][l];
        }
        __syncthreads();
    }
    if (tid < 16) spart[(size_t)n * 16 + tid] = sred[0][tid];
    for (int i = 0; i < 4; i++) {
        int idx = tid * 4 + i;
        if (idx < 1008) {
            int ht = 1 + (idx >> 4);
            int l = idx & 15;
            spart[((size_t)ht * 256 + n) * 16 + l] = 0.f;
        }
    }
}

// ---- attention: reduce spart -> softmax -> attn = A.w (packed into zap) ---------
__global__ void k_attn(const float* __restrict__ spart, const f16* __restrict__ A16T,
                       f16* __restrict__ zap) {
    int n = blockIdx.x;
    int tid = threadIdx.x;
    __shared__ float sred[16][17];
    __shared__ float sfin[16];
    int g = tid >> 4;
    int l = tid & 15;
    float p = 0.f;
#pragma unroll
    for (int i = 0; i < 4; i++)
        p += spart[((size_t)(g + i * 16) * 256 + n) * 16 + l];
    sred[g][l] = p;
    __syncthreads();
    if (tid < 16) {
        float s = 0.f;
#pragma unroll
        for (int gg = 0; gg < 16; gg++) s += sred[gg][tid];
        sfin[tid] = s;
    }
    __syncthreads();
    float w[16];
    float mx = -1e30f;
#pragma unroll
    for (int ll = 0; ll < 16; ll++) { w[ll] = sfin[ll] * 0.03125f; mx = fmaxf(mx, w[ll]); }
    float sum = 0.f;
#pragma unroll
    for (int ll = 0; ll < 16; ll++) { w[ll] = __expf(w[ll] - mx); sum += w[ll]; }
    float inv = 1.f / sum;
#pragma unroll
    for (int ll = 0; ll < 16; ll++) w[ll] *= inv;
    if (tid < 128) {
        int h = tid * 8;
        float acc[8];
#pragma unroll
        for (int e = 0; e < 8; e++) acc[e] = 0.f;
#pragma unroll
        for (int ll = 0; ll < 16; ll++) {
            f16x8 av = *(const f16x8*)(A16T + (size_t)n * 16384 + ll * 1024 + h);
#pragma unroll
            for (int e = 0; e < 8; e++) acc[e] += (float)av[e] * w[ll];
        }
        f16x8 hv;
#pragma unroll
        for (int e = 0; e < 8; e++) hv[e] = (f16)acc[e];
        *(f16x8*)(zap + ((size_t)(h >> 5) * 256 + n) * 32 + (h & 31)) = hv;
    }
}

// ---- one LSTM step, barrier-free register-streaming GEMM, packed operands -------
// grid 256 = 4 nt(64n) x 64 ht(16h); XCD = bid%8 = ht%8 -> 3 MB weight slice
// L2-resident. 512 thr = 8 waves; wave w owns K-slice [w*384,(w+1)*384), computes
// all 4 gates. Every K-loop load is one contiguous 1 KB transaction.
__global__ __launch_bounds__(512, 4) void k_step(
    const f16* __restrict__ xp, const f16* __restrict__ W3P,
    const f16* __restrict__ zin, f16* __restrict__ zout,
    const f16* __restrict__ zap, const f16* __restrict__ A16T,
    const float* __restrict__ b, float* __restrict__ c,
    float* __restrict__ spart, float* __restrict__ out, int t) {
    __shared__ float Gs[4][4][64 * 17];   // [slab][gate][nn*17+hh]  69.6 KB
    __shared__ float Hs[64 * 17];

    int tid = threadIdx.x;
    int wave = tid >> 6;
    int lane = tid & 63;
    int m16 = lane & 15;
    int quad = lane >> 4;
    int bid = blockIdx.x;
    int ht = bid & 63;
    int n0 = (bid >> 6) << 6;
    int hc = ht * 16;

    f32x4 acc[4][4];
#pragma unroll
    for (int g = 0; g < 4; g++)
#pragma unroll
        for (int m = 0; m < 4; m++) acc[g][m] = (f32x4){0.f, 0.f, 0.f, 0.f};

    const f16* brow[4];
#pragma unroll
    for (int g = 0; g < 4; g++)
        brow[g] = W3P + (size_t)((ht * 4 + g) * 96) * 512 + m16 * 32 + quad * 8;

    // A-fragment lane offset (same for xp/zin/zap): fragment mt covers n0+mt*16+m16
    size_t offm[4];
#pragma unroll
    for (int mt = 0; mt < 4; mt++)
        offm[mt] = (size_t)(n0 + mt * 16 + m16) * 32 + quad * 8;
    const f16* bx = xp + (size_t)t * 262144;   // t*32*256*32

    int sg0 = wave * 12;
#pragma unroll 2
    for (int s = 0; s < 12; s++) {
        int sg = sg0 + s;
        int seg = sg >> 5;
        int sl = sg & 31;
        const f16* base = (seg == 0) ? bx : ((seg == 1) ? zin : zap);
        base += (size_t)sl * 8192;             // sl*256*32
        f16x8 a[4], bb[4];
#pragma unroll
        for (int mt = 0; mt < 4; mt++) a[mt] = *(const f16x8*)(base + offm[mt]);
#pragma unroll
        for (int g = 0; g < 4; g++) bb[g] = *(const f16x8*)(brow[g] + (size_t)sg * 512);
#pragma unroll
        for (int g = 0; g < 4; g++)
#pragma unroll
            for (int mt = 0; mt < 4; mt++)
                acc[g][mt] = __builtin_amdgcn_mfma_f32_16x16x32_f16(a[mt], bb[g], acc[g][mt], 0, 0, 0);
    }

    // ---- reduce 8 K-slice waves via 4 slabs: write then owner-add ----
    if (wave < 4) {
#pragma unroll
        for (int g = 0; g < 4; g++)
#pragma unroll
            for (int mt = 0; mt < 4; mt++)
#pragma unroll
                for (int r = 0; r < 4; r++)
                    Gs[wave][g][(mt * 16 + quad * 4 + r) * 17 + m16] = acc[g][mt][r];
    }
    __syncthreads();
    if (wave >= 4) {
        int sl = wave - 4;
#pragma unroll
        for (int g = 0; g < 4; g++)
#pragma unroll
            for (int mt = 0; mt < 4; mt++)
#pragma unroll
                for (int r = 0; r < 4; r++)
                    Gs[sl][g][(mt * 16 + quad * 4 + r) * 17 + m16] += acc[g][mt][r];
    }
    __syncthreads();

    // ---- gates + state update: 64n x 16h = 1024, 2 per thread ----
    for (int i = 0; i < 2; i++) {
        int idx = i * 512 + tid;
        int nn = idx >> 4;
        int hh = idx & 15;
        int gi = nn * 17 + hh;
        int gn = n0 + nn;
        int gh = hc + hh;
        float ai = Gs[0][0][gi] + Gs[1][0][gi] + Gs[2][0][gi] + Gs[3][0][gi] + b[gh];
        float af = Gs[0][1][gi] + Gs[1][1][gi] + Gs[2][1][gi] + Gs[3][1][gi] + b[1024 + gh];
        float ao = Gs[0][2][gi] + Gs[1][2][gi] + Gs[2][2][gi] + Gs[3][2][gi] + b[2048 + gh];
        float ag = Gs[0][3][gi] + Gs[1][3][gi] + Gs[2][3][gi] + Gs[3][3][gi] + b[3072 + gh];
        float ig = 1.f / (1.f + __expf(-ai));
        float fg = 1.f / (1.f + __expf(-af));
        float og = 1.f / (1.f + __expf(-ao));
        float gg = tanhf(ag);
        float cn = fg * c[gn * 1024 + gh] + ig * gg;
        c[gn * 1024 + gh] = cn;
        float hn = og * tanhf(cn);
        out[((size_t)gn * T_ + t) * 1024 + gh] = hn;
        Hs[gi] = hn;
    }
    __syncthreads();

    // ---- packed h write: 64n x 16h, threads 0..127 write f16x8 ----
    if (tid < 128) {
        int nn = tid >> 1;
        int h0 = (tid & 1) * 8;
        f16x8 hv;
#pragma unroll
        for (int e = 0; e < 8; e++) hv[e] = (f16)Hs[nn * 17 + h0 + e];
        int gh = hc + h0;
        *(f16x8*)(zout + ((size_t)(gh >> 5) * 256 + (n0 + nn)) * 32 + (gh & 31)) = hv;
    }

    // ---- partial scores: 64n x 16l, 2 per thread, vectorized A16T reads ----
    for (int i = 0; i < 2; i++) {
        int idx = i * 512 + tid;
        int nn = idx >> 4;
        int l = idx & 15;
        int gn = n0 + nn;
        const f16* Ap = A16T + (size_t)gn * 16384 + l * 1024 + hc;
        f16x8 a0 = *(const f16x8*)Ap;
        f16x8 a1 = *(const f16x8*)(Ap + 8);
        float s = 0.f;
#pragma unroll
        for (int j = 0; j < 8; j++)
            s += Hs[nn * 17 + j] * (float)a0[j] + Hs[nn * 17 + 8 + j] * (float)a1[j];
        spart[((size_t)ht * 256 + gn) * 16 + l] = s;
    }
}

extern "C" void kernel_launch(void* const* d_in, const int* in_sizes, int n_in,
                              void* d_out, int out_size, void* d_ws, size_t ws_size,
                              hipStream_t stream) {
    const float* x     = (const float*)d_in[0];
    const float* A     = (const float*)d_in[1];
    const float* Wx    = (const float*)d_in[2];
    const float* Wh    = (const float*)d_in[3];
    const float* Wattn = (const float*)d_in[4];
    const float* b     = (const float*)d_in[5];
    float* out = (float*)d_out;

    char* ws = (char*)d_ws;
    size_t off = 0;
    f16* W3P  = (f16*)(ws + off); off += (size_t)G4 * K3 * 2;        // 25.2 MB
    f16* xp   = (f16*)(ws + off); off += (size_t)N_ * T_ * D_ * 2;   // 33.6 MB
    f16* A16T = (f16*)(ws + off); off += (size_t)N_ * H_ * 16 * 2;   // 8.4 MB
    f16* zp0  = (f16*)(ws + off); off += (size_t)N_ * H_ * 2;
    f16* zp1  = (f16*)(ws + off); off += (size_t)N_ * H_ * 2;
    f16* zap  = (f16*)(ws + off); off += (size_t)N_ * H_ * 2;
    float* c  = (float*)(ws + off); off += (size_t)N_ * H_ * 4;      // 1 MB
    float* spart = (float*)(ws + off); off += (size_t)64 * N_ * 16 * 4; // 1 MB

    k_transpose<<<dim3(128, 96), dim3(32, 8), 0, stream>>>(Wx, Wh, Wattn, W3P);
    k_packX<<<16384, 128, 0, stream>>>(x, xp);
    k_packA<<<256, 256, 0, stream>>>(A, A16T);
    k_init<<<256, 256, 0, stream>>>(A, zp0, c, spart);
    for (int t = 0; t < T_; t++) {
        f16* zin  = (t & 1) ? zp1 : zp0;
        f16* zout = (t & 1) ? zp0 : zp1;
        k_attn<<<256, 256, 0, stream>>>(spart, A16T, zap);
        k_step<<<256, 512, 0, stream>>>(xp, W3P, zin, zout, zap, A16T, b, c, spart, out, t);
    }
}